// Round 1
// baseline (11697.830 us; speedup 1.0000x reference)
//
#include <hip/hip_runtime.h>

// ============================================================================
// RSSM (DynamicsModel) on MI355X.
// B=256, T=64, H=2048, S=512, A=64, E=2048.  63 sequential steps.
// Strategy: precompute all t-independent GEMM contributions (action/obs
// projections) in parallel once; per step run 5 bf16-MFMA GEMMs (m97-style
// 128x128 tile) + 2 tiny elementwise kernels. All on one stream.
// ============================================================================

typedef __attribute__((ext_vector_type(8))) short bf16x8;
typedef __attribute__((ext_vector_type(4))) float f32x4;
typedef __attribute__((ext_vector_type(4))) short s16x4;

#define DEVI static __device__ __forceinline__

DEVI float bf2f(short s) { union { float f; unsigned u; } v; v.u = ((unsigned)(unsigned short)s) << 16; return v.f; }
DEVI short f2bf(float f) {
  union { float f; unsigned u; } v; v.f = f;
  unsigned r = v.u + 0x7FFFu + ((v.u >> 16) & 1u);   // RNE
  return (short)(r >> 16);
}

// ---- problem constants -----------------------------------------------------
#define Bsz 256
#define Tsz 64
#define Hsz 2048
#define Ssz 512
#define Asz 64
#define Esz 2048
#define TM1 63

// output layout (float offsets)
#define OUT_PS  33554432L   // prior_states   [B,64,512]
#define OUT_QS  41943040L   // posterior      [B,64,512]
#define OUT_PM  50331648L   // pm  [B,63,512]
#define OUT_PLV 58589184L
#define OUT_QM  66846720L
#define OUT_QLV 75104256L

// ============================================================================
// Generic bf16 GEMM:  C[M,N] = A[M,K] (bf16) @ Bt[N,K]^T (bf16), fp32 accum.
// 128x128 tile, BK=64, 4 waves (each 64x64 = 4x4 frags of 16x16x32 MFMA),
// global_load_lds width 16 staging (m97 structure).
// blockIdx.z selects between two independent GEMMs of identical M,N,K.
// ============================================================================
struct GArg {
  const short* A; const short* Bt; const float* bias; const short* Ci;
  float* oF; short* oB;
  int lda, ldb, ldoF, ldoB; long ldci;
};

template<int HASBIAS, int HASCI, int RELU, int OUTF, int OUTB>
__global__ __launch_bounds__(256) void gemm_bt(GArg g0, GArg g1, int M, int N, int K) {
  GArg g = (blockIdx.z == 0) ? g0 : g1;
  __shared__ __align__(16) short As[128 * 64];
  __shared__ __align__(16) short Bs[128 * 64];
  const int tid = threadIdx.x;
  const int w = tid >> 6, l = tid & 63;
  const int bm0 = blockIdx.y << 7, bn0 = blockIdx.x << 7;
  const int fc = l & 15, fh = l >> 4;                 // frag col / k-group
  const int wr = (w >> 1) << 6, wc = (w & 1) << 6;    // wave's 64x64 sub-tile
  f32x4 acc[4][4];
#pragma unroll
  for (int i = 0; i < 4; ++i)
#pragma unroll
    for (int j = 0; j < 4; ++j) acc[i][j] = f32x4{0.f, 0.f, 0.f, 0.f};

  const int nk = K >> 6;
  for (int kt = 0; kt < nk; ++kt) {
#pragma unroll
    for (int i = 0; i < 4; ++i) {
      const int instbase = ((i << 2) + w) << 10;       // wave-uniform LDS byte base
      const int boff = instbase + (l << 4);            // this lane's dest byte
      const int row = boff >> 7;                       // tile row (128B rows)
      const int cole = (boff & 127) >> 1;              // element col within BK
      const long gA = (long)(bm0 + row) * g.lda + (kt << 6) + cole;
      const long gB = (long)(bn0 + row) * g.ldb + (kt << 6) + cole;
      __builtin_amdgcn_global_load_lds(
          (const __attribute__((address_space(1))) void*)(g.A + gA),
          (__attribute__((address_space(3))) void*)((char*)As + instbase), 16, 0, 0);
      __builtin_amdgcn_global_load_lds(
          (const __attribute__((address_space(1))) void*)(g.Bt + gB),
          (__attribute__((address_space(3))) void*)((char*)Bs + instbase), 16, 0, 0);
    }
    __syncthreads();   // compiler emits vmcnt(0) drain before barrier
#pragma unroll
    for (int kk = 0; kk < 2; ++kk) {
      bf16x8 af[4], bb[4];
#pragma unroll
      for (int mi = 0; mi < 4; ++mi)
        af[mi] = *(const bf16x8*)&As[(wr + (mi << 4) + fc) * 64 + (kk << 5) + (fh << 3)];
#pragma unroll
      for (int ni = 0; ni < 4; ++ni)
        bb[ni] = *(const bf16x8*)&Bs[(wc + (ni << 4) + fc) * 64 + (kk << 5) + (fh << 3)];
#pragma unroll
      for (int mi = 0; mi < 4; ++mi)
#pragma unroll
        for (int ni = 0; ni < 4; ++ni)
          acc[mi][ni] = __builtin_amdgcn_mfma_f32_16x16x32_bf16(af[mi], bb[ni], acc[mi][ni], 0, 0, 0);
    }
    __syncthreads();
  }
  // epilogue: D col = lane&15, row = (lane>>4)*4 + r  [guide §3, m89-verified]
#pragma unroll
  for (int mi = 0; mi < 4; ++mi) {
#pragma unroll
    for (int ni = 0; ni < 4; ++ni) {
      const int n = bn0 + wc + (ni << 4) + fc;
      float bv = 0.f;
      if (HASBIAS) bv = g.bias[n];
#pragma unroll
      for (int r = 0; r < 4; ++r) {
        const int m = bm0 + wr + (mi << 4) + (fh << 2) + r;
        float v = acc[mi][ni][r] + bv;
        if (HASCI) v += bf2f(g.Ci[(long)m * g.ldci + n]);
        if (RELU) v = fmaxf(v, 0.f);
        if (OUTF) g.oF[(long)m * g.ldoF + n] = v;
        if (OUTB) g.oB[(long)m * g.ldoB + n] = f2bf(v);
      }
    }
  }
}

// ============================================================================
// small kernels
// ============================================================================

// flat fp32 -> bf16 convert (n multiple of 4)
__global__ void conv_f2b(const float* __restrict__ src, short* __restrict__ dst, long n) {
  long i = ((long)blockIdx.x * 256 + threadIdx.x) * 4;
  const long stride = (long)gridDim.x * 1024;
  for (; i < n; i += stride) {
    float4 v = *(const float4*)(src + i);
    s16x4 o;
    o[0] = f2bf(v.x); o[1] = f2bf(v.y); o[2] = f2bf(v.z); o[3] = f2bf(v.w);
    *(s16x4*)(dst + i) = o;
  }
}

// dst[n][k] = src[(k0+k)*srcld + n]  (transpose + convert), dims multiples of 32
__global__ void transp(const float* __restrict__ src, short* __restrict__ dst,
                       int srcld, int k0, int K, int N) {
  __shared__ float t[32][33];
  const int tx = threadIdx.x, ty = threadIdx.y;
  const int kb = blockIdx.y << 5, nb = blockIdx.x << 5;
#pragma unroll
  for (int i = ty; i < 32; i += 8)
    t[i][tx] = src[(long)(k0 + kb + i) * srcld + nb + tx];
  __syncthreads();
#pragma unroll
  for (int i = ty; i < 32; i += 8)
    dst[(long)(nb + i) * K + kb + tx] = f2bf(t[tx][i]);
}

// initial state: hiddens[:,0,:], prior/posterior_states[:,0,:], h_b, s_b
__global__ void init_kernel(const float* __restrict__ ph, const float* __restrict__ ps,
                            float* __restrict__ out, short* __restrict__ hb, short* __restrict__ sb) {
  const int idx = blockIdx.x * 256 + threadIdx.x;   // 524288
  const int b = idx >> 11, n = idx & 2047;
  const float h = ph[idx];
  out[(long)b * (Tsz * Hsz) + n] = h;
  hb[idx] = f2bf(h);
  if (n < Ssz) {
    const int sidx = b * Ssz + n;
    const float s = ps[sidx];
    out[OUT_PS + (long)b * (Tsz * Ssz) + n] = s;
    out[OUT_QS + (long)b * (Tsz * Ssz) + n] = s;
    sb[sidx] = f2bf(s);
  }
}

// GRU gate fusion. hold/hnew bases already offset by t*H / (t+1)*H.
__global__ void gru_kernel(const float* __restrict__ gi, const float* __restrict__ gh,
                           const float* __restrict__ hold, float* __restrict__ hnew,
                           short* __restrict__ hb) {
  const int idx = blockIdx.x * 256 + threadIdx.x;   // 524288
  const int b = idx >> 11, n = idx & 2047;
  const long gb = (long)b * (3 * Hsz) + n;
  const float r  = 1.f / (1.f + expf(-(gi[gb] + gh[gb])));
  const float z  = 1.f / (1.f + expf(-(gi[gb + Hsz] + gh[gb + Hsz])));
  const float nn = tanhf(gi[gb + 2 * Hsz] + r * gh[gb + 2 * Hsz]);
  const float h  = (1.f - z) * nn + z * hold[(long)b * (Tsz * Hsz) + n];
  hnew[(long)b * (Tsz * Hsz) + n] = h;
  hb[idx] = f2bf(h);
}

// rsample: exp(softplus(x)) == 1 + e^x exactly
__global__ void sample_kernel(const float* __restrict__ pr, const float* __restrict__ po,
                              const float* __restrict__ pn, const float* __restrict__ qn,
                              float* __restrict__ out, short* __restrict__ sb, int t) {
  const int idx = blockIdx.x * 256 + threadIdx.x;   // 131072
  const int b = idx >> 9, j = idx & 511;
  const float pm  = pr[(long)b * 1024 + j],  plv = pr[(long)b * 1024 + 512 + j];
  const float qm  = po[(long)b * 1024 + j],  qlv = po[(long)b * 1024 + 512 + j];
  const long noff = ((long)b * TM1 + t) * Ssz + j;
  const float psv = pm + (1.f + expf(plv)) * pn[noff];
  const float qsv = qm + (1.f + expf(qlv)) * qn[noff];
  out[OUT_PS + (long)b * (Tsz * Ssz) + (long)(t + 1) * Ssz + j] = psv;
  out[OUT_QS + (long)b * (Tsz * Ssz) + (long)(t + 1) * Ssz + j] = qsv;
  out[OUT_PM  + noff] = pm;
  out[OUT_PLV + noff] = plv;
  out[OUT_QM  + noff] = qm;
  out[OUT_QLV + noff] = qlv;
  sb[idx] = f2bf(qsv);
}

// ============================================================================
// host
// ============================================================================
static GArg mk(const short* A, int lda, const short* Bt, int ldb, const float* bias,
               const short* Ci, long ldci, float* oF, int ldoF, short* oB, int ldoB) {
  GArg g; g.A = A; g.Bt = Bt; g.bias = bias; g.Ci = Ci; g.ldci = ldci;
  g.oF = oF; g.oB = oB; g.lda = lda; g.ldb = ldb; g.ldoF = ldoF; g.ldoB = ldoB;
  return g;
}

extern "C" void kernel_launch(void* const* d_in, const int* in_sizes, int n_in,
                              void* d_out, int out_size, void* d_ws, size_t ws_size,
                              hipStream_t stream) {
  const float* prev_hidden = (const float*)d_in[0];
  const float* prev_state  = (const float*)d_in[1];
  const float* actions     = (const float*)d_in[2];
  const float* obs         = (const float*)d_in[3];
  const float* prior_noise = (const float*)d_in[4];
  const float* post_noise  = (const float*)d_in[5];
  const float* W_sa = (const float*)d_in[6];
  const float* b_sa = (const float*)d_in[7];
  const float* W_ih = (const float*)d_in[8];
  const float* W_hh = (const float*)d_in[9];
  const float* b_ih = (const float*)d_in[10];
  const float* b_hh = (const float*)d_in[11];
  const float* W_ha = (const float*)d_in[12];
  const float* b_ha = (const float*)d_in[13];
  const float* W_prior = (const float*)d_in[14];
  const float* b_prior = (const float*)d_in[15];
  const float* W_ho = (const float*)d_in[16];
  const float* b_ho = (const float*)d_in[17];
  const float* W_post = (const float*)d_in[18];
  const float* b_post = (const float*)d_in[19];
  float* out = (float*)d_out;

  // ---- workspace carve-up (~376 MB total) ----------------------------------
  char* p = (char*)d_ws;
  auto alloc = [&](size_t bytes) { char* r = p; p += (bytes + 255) & ~(size_t)255; return r; };
  short* Wih_b   = (short*)alloc(3L * Hsz * Hsz * 2);      // [6144,2048]
  short* Whh_b   = (short*)alloc(3L * Hsz * Hsz * 2);
  short* Wt_sa_s = (short*)alloc((long)Hsz * Ssz * 2);     // [2048,512]
  short* Wt_sa_a = (short*)alloc((long)Hsz * Asz * 2);     // [2048,64]
  short* Wt_ha_h = (short*)alloc((long)Hsz * Hsz * 2);
  short* Wt_ha_a = (short*)alloc((long)Hsz * Asz * 2);
  short* Wt_ho_h = (short*)alloc((long)Hsz * Hsz * 2);
  short* Wt_ho_o = (short*)alloc((long)Hsz * Esz * 2);
  short* Wt_pr   = (short*)alloc(2L * Ssz * Hsz * 2);      // [1024,2048]
  short* Wt_po   = (short*)alloc(2L * Ssz * Hsz * 2);
  short* obs_b   = (short*)alloc((long)Bsz * Tsz * Esz * 2);
  short* act_b   = (short*)alloc((long)Bsz * Tsz * Asz * 2);
  short* a_pre   = (short*)alloc((long)Bsz * Tsz * Hsz * 2);   // a@Wsa_a + b_sa
  short* ha_a    = (short*)alloc((long)Bsz * Tsz * Hsz * 2);   // a@Wha_a + b_ha
  short* ho_o    = (short*)alloc((long)Bsz * Tsz * Hsz * 2);   // o@Who_o + b_ho
  short* s_b     = (short*)alloc((long)Bsz * Ssz * 2);
  short* h_b     = (short*)alloc((long)Bsz * Hsz * 2);
  short* sa_b    = (short*)alloc((long)Bsz * Hsz * 2);
  short* ha_b    = (short*)alloc((long)Bsz * Hsz * 2);
  short* ho_b    = (short*)alloc((long)Bsz * Hsz * 2);
  float* gi_f    = (float*)alloc((long)Bsz * 3 * Hsz * 4);
  float* gh_f    = (float*)alloc((long)Bsz * 3 * Hsz * 4);
  float* pr_f    = (float*)alloc((long)Bsz * 2 * Ssz * 4);
  float* po_f    = (float*)alloc((long)Bsz * 2 * Ssz * 4);
  (void)ws_size; (void)in_sizes; (void)n_in; (void)out_size;

  // ---- setup: conversions / transposes --------------------------------------
  conv_f2b<<<4096, 256, 0, stream>>>(obs,  obs_b, (long)Bsz * Tsz * Esz);
  conv_f2b<<<1024, 256, 0, stream>>>(actions, act_b, (long)Bsz * Tsz * Asz);
  conv_f2b<<<4096, 256, 0, stream>>>(W_ih, Wih_b, 3L * Hsz * Hsz);
  conv_f2b<<<4096, 256, 0, stream>>>(W_hh, Whh_b, 3L * Hsz * Hsz);

  dim3 tb(32, 8);
  transp<<<dim3(Hsz / 32, Ssz / 32), tb, 0, stream>>>(W_sa, Wt_sa_s, Hsz, 0,   Ssz, Hsz);
  transp<<<dim3(Hsz / 32, Asz / 32), tb, 0, stream>>>(W_sa, Wt_sa_a, Hsz, Ssz, Asz, Hsz);
  transp<<<dim3(Hsz / 32, Hsz / 32), tb, 0, stream>>>(W_ha, Wt_ha_h, Hsz, 0,   Hsz, Hsz);
  transp<<<dim3(Hsz / 32, Asz / 32), tb, 0, stream>>>(W_ha, Wt_ha_a, Hsz, Hsz, Asz, Hsz);
  transp<<<dim3(Hsz / 32, Hsz / 32), tb, 0, stream>>>(W_ho, Wt_ho_h, Hsz, 0,   Hsz, Hsz);
  transp<<<dim3(Hsz / 32, Esz / 32), tb, 0, stream>>>(W_ho, Wt_ho_o, Hsz, Hsz, Esz, Hsz);
  transp<<<dim3(2 * Ssz / 32, Hsz / 32), tb, 0, stream>>>(W_prior, Wt_pr, 2 * Ssz, 0, Hsz, 2 * Ssz);
  transp<<<dim3(2 * Ssz / 32, Hsz / 32), tb, 0, stream>>>(W_post,  Wt_po, 2 * Ssz, 0, Hsz, 2 * Ssz);

  init_kernel<<<2048, 256, 0, stream>>>(prev_hidden, prev_state, out, h_b, s_b);

  // ---- t-independent precomputes (parallel GEMMs over all B*T rows) --------
  {
    GArg g0 = mk(act_b, Asz, Wt_sa_a, Asz, b_sa, nullptr, 0, nullptr, 0, a_pre, Hsz);
    GArg g1 = mk(act_b, Asz, Wt_ha_a, Asz, b_ha, nullptr, 0, nullptr, 0, ha_a, Hsz);
    gemm_bt<1, 0, 0, 0, 1><<<dim3(Hsz / 128, (Bsz * Tsz) / 128, 2), 256, 0, stream>>>(
        g0, g1, Bsz * Tsz, Hsz, Asz);
  }
  {
    GArg g0 = mk(obs_b, Esz, Wt_ho_o, Esz, b_ho, nullptr, 0, nullptr, 0, ho_o, Hsz);
    gemm_bt<1, 0, 0, 0, 1><<<dim3(Hsz / 128, (Bsz * Tsz) / 128, 1), 256, 0, stream>>>(
        g0, g0, Bsz * Tsz, Hsz, Esz);
  }

  // ---- sequential scan -------------------------------------------------------
  const long ldPre = (long)Tsz * Hsz;   // row stride (per b) inside precompute bufs
  for (int t = 0; t < TM1; ++t) {
    // sa = relu(s @ Wsa_s + a_pre[t])           [256,2048] K=512
    {
      GArg g0 = mk(s_b, Ssz, Wt_sa_s, Ssz, nullptr, a_pre + (long)t * Hsz, ldPre,
                   nullptr, 0, sa_b, Hsz);
      gemm_bt<0, 1, 1, 0, 1><<<dim3(16, 2, 1), 256, 0, stream>>>(g0, g0, Bsz, Hsz, Ssz);
    }
    // gi = sa @ Wih^T + b_ih ; gh = h @ Whh^T + b_hh    [256,6144] K=2048
    {
      GArg g0 = mk(sa_b, Hsz, Wih_b, Hsz, b_ih, nullptr, 0, gi_f, 3 * Hsz, nullptr, 0);
      GArg g1 = mk(h_b,  Hsz, Whh_b, Hsz, b_hh, nullptr, 0, gh_f, 3 * Hsz, nullptr, 0);
      gemm_bt<1, 0, 0, 1, 0><<<dim3(48, 2, 2), 256, 0, stream>>>(g0, g1, Bsz, 3 * Hsz, Hsz);
    }
    gru_kernel<<<2048, 256, 0, stream>>>(gi_f, gh_f, out + (long)t * Hsz,
                                         out + (long)(t + 1) * Hsz, h_b);
    // ha = relu(h @ Wha_h + ha_a[t]) ; ho = relu(h @ Who_h + ho_o[t])
    {
      GArg g0 = mk(h_b, Hsz, Wt_ha_h, Hsz, nullptr, ha_a + (long)t * Hsz, ldPre,
                   nullptr, 0, ha_b, Hsz);
      GArg g1 = mk(h_b, Hsz, Wt_ho_h, Hsz, nullptr, ho_o + (long)t * Hsz, ldPre,
                   nullptr, 0, ho_b, Hsz);
      gemm_bt<0, 1, 1, 0, 1><<<dim3(16, 2, 2), 256, 0, stream>>>(g0, g1, Bsz, Hsz, Hsz);
    }
    // prior = ha @ Wpr^T + b_prior ; post = ho @ Wpo^T + b_post   [256,1024]
    {
      GArg g0 = mk(ha_b, Hsz, Wt_pr, Hsz, b_prior, nullptr, 0, pr_f, 2 * Ssz, nullptr, 0);
      GArg g1 = mk(ho_b, Hsz, Wt_po, Hsz, b_post,  nullptr, 0, po_f, 2 * Ssz, nullptr, 0);
      gemm_bt<1, 0, 0, 1, 0><<<dim3(8, 2, 2), 256, 0, stream>>>(g0, g1, Bsz, 2 * Ssz, Hsz);
    }
    sample_kernel<<<512, 256, 0, stream>>>(pr_f, po_f, prior_noise, post_noise, out, s_b, t);
  }
}

// Round 2
// 6638.145 us; speedup vs baseline: 1.7622x; 1.7622x over previous
//
#include <hip/hip_runtime.h>

// ============================================================================
// RSSM (DynamicsModel) on MI355X — round 2.
//   * GEMM: double-buffered LDS w/ counted vmcnt(8) (raw s_barrier, no drain)
//   * GEMM: XOR-swizzled LDS (slot ^= row&7) via pre-swizzled global source
//   * split-K=4 for ha/ho and prior/post; reducer/sample sum fp32 partials
//   * partial buffers alias the (dead-after-precompute) obs_b region
// ============================================================================

typedef __attribute__((ext_vector_type(8))) short bf16x8;
typedef __attribute__((ext_vector_type(4))) float f32x4;
typedef __attribute__((ext_vector_type(4))) short s16x4;

#define DEVI static __device__ __forceinline__

DEVI float bf2f(short s) { union { float f; unsigned u; } v; v.u = ((unsigned)(unsigned short)s) << 16; return v.f; }
DEVI short f2bf(float f) {
  union { float f; unsigned u; } v; v.f = f;
  unsigned r = v.u + 0x7FFFu + ((v.u >> 16) & 1u);   // RNE
  return (short)(r >> 16);
}

#define Bsz 256
#define Tsz 64
#define Hsz 2048
#define Ssz 512
#define Asz 64
#define Esz 2048
#define TM1 63

#define PSH (256 * 2048)
#define PSS (256 * 1024)

#define OUT_PS  33554432L
#define OUT_QS  41943040L
#define OUT_PM  50331648L
#define OUT_PLV 58589184L
#define OUT_QM  66846720L
#define OUT_QLV 75104256L

struct GArg {
  const short* A; const short* Bt; const float* bias; const short* Ci;
  float* oF; short* oB;
  int lda, ldb, ldoF, ldoB; long ldci, pstride;
};

template<int HASBIAS, int HASCI, int RELU, int OUTF, int OUTB>
__global__ __launch_bounds__(256) void gemm_bt(GArg g0, GArg g1, int kcK) {
  const int gemm = blockIdx.z & 1, kc = blockIdx.z >> 1;
  const GArg g = gemm ? g1 : g0;
  const short* __restrict__ Ag = g.A + (long)kc * kcK;
  const short* __restrict__ Bg = g.Bt + (long)kc * kcK;
  __shared__ __align__(16) short As[2][128 * 64];
  __shared__ __align__(16) short Bs[2][128 * 64];
  const int tid = threadIdx.x;
  const int w = tid >> 6, l = tid & 63;
  const int bm0 = blockIdx.y << 7, bn0 = blockIdx.x << 7;
  const int fc = l & 15, fh = l >> 4;
  const int wr = (w >> 1) << 6, wc = (w & 1) << 6;
  const int rx = fc & 7;

  const int srccol = ((l & 7) ^ ((l >> 3) & 7)) << 3;
  long aoff[4], boff[4];
#pragma unroll
  for (int i = 0; i < 4; ++i) {
    const int row = (((i << 2) + w) << 3) + (l >> 3);
    aoff[i] = (long)(bm0 + row) * g.lda + srccol;
    boff[i] = (long)(bn0 + row) * g.ldb + srccol;
  }

  f32x4 acc[4][4];
#pragma unroll
  for (int i = 0; i < 4; ++i)
#pragma unroll
    for (int j = 0; j < 4; ++j) acc[i][j] = f32x4{0.f, 0.f, 0.f, 0.f};

  auto STAGE = [&](int kt, int buf) {
#pragma unroll
    for (int i = 0; i < 4; ++i) {
      const int ib = ((i << 2) + w) << 10;
      __builtin_amdgcn_global_load_lds(
          (const __attribute__((address_space(1))) void*)(Ag + aoff[i] + (kt << 6)),
          (__attribute__((address_space(3))) void*)((char*)&As[buf][0] + ib), 16, 0, 0);
      __builtin_amdgcn_global_load_lds(
          (const __attribute__((address_space(1))) void*)(Bg + boff[i] + (kt << 6)),
          (__attribute__((address_space(3))) void*)((char*)&Bs[buf][0] + ib), 16, 0, 0);
    }
  };
  auto COMPUTE = [&](int buf) {
#pragma unroll
    for (int kk = 0; kk < 2; ++kk) {
      bf16x8 af[4], bb[4];
#pragma unroll
      for (int mi = 0; mi < 4; ++mi)
        af[mi] = *(const bf16x8*)&As[buf][(wr + (mi << 4) + fc) * 64 + ((((kk << 2) + fh) ^ rx) << 3)];
#pragma unroll
      for (int ni = 0; ni < 4; ++ni)
        bb[ni] = *(const bf16x8*)&Bs[buf][(wc + (ni << 4) + fc) * 64 + ((((kk << 2) + fh) ^ rx) << 3)];
#pragma unroll
      for (int mi = 0; mi < 4; ++mi)
#pragma unroll
        for (int ni = 0; ni < 4; ++ni)
          acc[mi][ni] = __builtin_amdgcn_mfma_f32_16x16x32_bf16(af[mi], bb[ni], acc[mi][ni], 0, 0, 0);
    }
  };

  const int nk = kcK >> 6;
  STAGE(0, 0);
  for (int kt = 0; kt < nk - 1; ++kt) {
    STAGE(kt + 1, (kt + 1) & 1);
    asm volatile("s_waitcnt vmcnt(8)" ::: "memory");
    __builtin_amdgcn_s_barrier();
    __builtin_amdgcn_sched_barrier(0);
    COMPUTE(kt & 1);
    asm volatile("s_waitcnt lgkmcnt(0)" ::: "memory");
    __builtin_amdgcn_s_barrier();
  }
  asm volatile("s_waitcnt vmcnt(0)" ::: "memory");
  __builtin_amdgcn_s_barrier();
  __builtin_amdgcn_sched_barrier(0);
  COMPUTE((nk - 1) & 1);

  float* oF = OUTF ? (g.oF + (long)kc * g.pstride) : (float*)nullptr;
#pragma unroll
  for (int mi = 0; mi < 4; ++mi) {
#pragma unroll
    for (int ni = 0; ni < 4; ++ni) {
      const int n = bn0 + wc + (ni << 4) + fc;
      float bv = 0.f;
      if (HASBIAS) bv = g.bias[n];
#pragma unroll
      for (int r = 0; r < 4; ++r) {
        const int m = bm0 + wr + (mi << 4) + (fh << 2) + r;
        float v = acc[mi][ni][r] + bv;
        if (HASCI) v += bf2f(g.Ci[(long)m * g.ldci + n]);
        if (RELU) v = fmaxf(v, 0.f);
        if (OUTF) oF[(long)m * g.ldoF + n] = v;
        if (OUTB) g.oB[(long)m * g.ldoB + n] = f2bf(v);
      }
    }
  }
}

__global__ void conv_f2b(const float* __restrict__ src, short* __restrict__ dst, long n) {
  long i = ((long)blockIdx.x * 256 + threadIdx.x) * 4;
  const long stride = (long)gridDim.x * 1024;
  for (; i < n; i += stride) {
    float4 v = *(const float4*)(src + i);
    s16x4 o;
    o[0] = f2bf(v.x); o[1] = f2bf(v.y); o[2] = f2bf(v.z); o[3] = f2bf(v.w);
    *(s16x4*)(dst + i) = o;
  }
}

__global__ void transp(const float* __restrict__ src, short* __restrict__ dst,
                       int srcld, int k0, int K, int N) {
  __shared__ float t[32][33];
  const int tx = threadIdx.x, ty = threadIdx.y;
  const int kb = blockIdx.y << 5, nb = blockIdx.x << 5;
#pragma unroll
  for (int i = ty; i < 32; i += 8)
    t[i][tx] = src[(long)(k0 + kb + i) * srcld + nb + tx];
  __syncthreads();
#pragma unroll
  for (int i = ty; i < 32; i += 8)
    dst[(long)(nb + i) * K + kb + tx] = f2bf(t[tx][i]);
}

__global__ void init_kernel(const float* __restrict__ ph, const float* __restrict__ ps,
                            float* __restrict__ out, short* __restrict__ hb, short* __restrict__ sb) {
  const int idx = blockIdx.x * 256 + threadIdx.x;
  const int b = idx >> 11, n = idx & 2047;
  const float h = ph[idx];
  out[(long)b * (Tsz * Hsz) + n] = h;
  hb[idx] = f2bf(h);
  if (n < Ssz) {
    const int sidx = b * Ssz + n;
    const float s = ps[sidx];
    out[OUT_PS + (long)b * (Tsz * Ssz) + n] = s;
    out[OUT_QS + (long)b * (Tsz * Ssz) + n] = s;
    sb[sidx] = f2bf(s);
  }
}

__global__ void gru_kernel(const float* __restrict__ gi, const float* __restrict__ gh,
                           const float* __restrict__ b_ih, const float* __restrict__ b_hh,
                           const float* __restrict__ hold, float* __restrict__ hnew,
                           short* __restrict__ hb) {
  const int idx = blockIdx.x * 256 + threadIdx.x;
  const int b = idx >> 11, n = idx & 2047;
  const long gb = (long)b * (3 * Hsz) + n;
  const float ir = gi[gb] + b_ih[n],                 hr = gh[gb] + b_hh[n];
  const float iz = gi[gb + Hsz] + b_ih[Hsz + n],     hz = gh[gb + Hsz] + b_hh[Hsz + n];
  const float in_ = gi[gb + 2 * Hsz] + b_ih[2 * Hsz + n];
  const float hn = gh[gb + 2 * Hsz] + b_hh[2 * Hsz + n];
  const float r = 1.f / (1.f + expf(-(ir + hr)));
  const float z = 1.f / (1.f + expf(-(iz + hz)));
  const float nn = tanhf(in_ + r * hn);
  const float h = (1.f - z) * nn + z * hold[(long)b * (Tsz * Hsz) + n];
  hnew[(long)b * (Tsz * Hsz) + n] = h;
  hb[idx] = f2bf(h);
}

__global__ void reduce_relu4(const float* __restrict__ p, const short* __restrict__ ciA,
                             const short* __restrict__ ciB, short* __restrict__ oA,
                             short* __restrict__ oB, int t) {
  const int z = blockIdx.y;
  const float* pz = p + (long)z * 4 * PSH;
  const short* ci = z ? ciB : ciA;
  short* o = z ? oB : oA;
  const int i = (blockIdx.x * 256 + threadIdx.x) * 4;
  const int b = i >> 11, n = i & 2047;
  f32x4 v = *(const f32x4*)&pz[i];
  v += *(const f32x4*)&pz[PSH + i];
  v += *(const f32x4*)&pz[2 * PSH + i];
  v += *(const f32x4*)&pz[3 * PSH + i];
  const s16x4 c = *(const s16x4*)&ci[((long)b * Tsz + t) * Hsz + n];
  s16x4 ov;
#pragma unroll
  for (int k = 0; k < 4; ++k) ov[k] = f2bf(fmaxf(v[k] + bf2f(c[k]), 0.f));
  *(s16x4*)&o[i] = ov;
}

__global__ void sample_kernel(const float* __restrict__ pp,
                              const float* __restrict__ bp, const float* __restrict__ bq,
                              const float* __restrict__ pn, const float* __restrict__ qn,
                              float* __restrict__ out, short* __restrict__ sb, int t) {
  const int idx = blockIdx.x * 256 + threadIdx.x;
  const int b = idx >> 9, j = idx & 511;
  const float* pr = pp;
  const float* po = pp + 4L * PSS;
  const long r0 = (long)b * 1024 + j;
  float pm = bp[j], plv = bp[512 + j], qm = bq[j], qlv = bq[512 + j];
#pragma unroll
  for (int k = 0; k < 4; ++k) {
    pm  += pr[k * PSS + r0];  plv += pr[k * PSS + r0 + 512];
    qm  += po[k * PSS + r0];  qlv += po[k * PSS + r0 + 512];
  }
  const long noff = ((long)b * TM1 + t) * Ssz + j;
  const float psv = pm + (1.f + expf(plv)) * pn[noff];
  const float qsv = qm + (1.f + expf(qlv)) * qn[noff];
  out[OUT_PS + (long)b * (Tsz * Ssz) + (long)(t + 1) * Ssz + j] = psv;
  out[OUT_QS + (long)b * (Tsz * Ssz) + (long)(t + 1) * Ssz + j] = qsv;
  out[OUT_PM  + noff] = pm;
  out[OUT_PLV + noff] = plv;
  out[OUT_QM  + noff] = qm;
  out[OUT_QLV + noff] = qlv;
  sb[idx] = f2bf(qsv);
}

static GArg mk(const short* A, int lda, const short* Bt, int ldb, const float* bias,
               const short* Ci, long ldci, float* oF, int ldoF, long pstride,
               short* oB, int ldoB) {
  GArg g; g.A = A; g.Bt = Bt; g.bias = bias; g.Ci = Ci; g.ldci = ldci;
  g.oF = oF; g.oB = oB; g.lda = lda; g.ldb = ldb; g.ldoF = ldoF; g.ldoB = ldoB;
  g.pstride = pstride;
  return g;
}

extern "C" void kernel_launch(void* const* d_in, const int* in_sizes, int n_in,
                              void* d_out, int out_size, void* d_ws, size_t ws_size,
                              hipStream_t stream) {
  const float* prev_hidden = (const float*)d_in[0];
  const float* prev_state  = (const float*)d_in[1];
  const float* actions     = (const float*)d_in[2];
  const float* obs         = (const float*)d_in[3];
  const float* prior_noise = (const float*)d_in[4];
  const float* post_noise  = (const float*)d_in[5];
  const float* W_sa = (const float*)d_in[6];
  const float* b_sa = (const float*)d_in[7];
  const float* W_ih = (const float*)d_in[8];
  const float* W_hh = (const float*)d_in[9];
  const float* b_ih = (const float*)d_in[10];
  const float* b_hh = (const float*)d_in[11];
  const float* W_ha = (const float*)d_in[12];
  const float* b_ha = (const float*)d_in[13];
  const float* W_prior = (const float*)d_in[14];
  const float* b_prior = (const float*)d_in[15];
  const float* W_ho = (const float*)d_in[16];
  const float* b_ho = (const float*)d_in[17];
  const float* W_post = (const float*)d_in[18];
  const float* b_post = (const float*)d_in[19];
  float* out = (float*)d_out;

  char* p = (char*)d_ws;
  auto alloc = [&](size_t bytes) { char* r = p; p += (bytes + 255) & ~(size_t)255; return r; };
  short* Wih_b   = (short*)alloc(3L * Hsz * Hsz * 2);
  short* Whh_b   = (short*)alloc(3L * Hsz * Hsz * 2);
  short* Wt_sa_s = (short*)alloc((long)Hsz * Ssz * 2);
  short* Wt_sa_a = (short*)alloc((long)Hsz * Asz * 2);
  short* Wt_ha_h = (short*)alloc((long)Hsz * Hsz * 2);
  short* Wt_ha_a = (short*)alloc((long)Hsz * Asz * 2);
  short* Wt_ho_h = (short*)alloc((long)Hsz * Hsz * 2);
  short* Wt_ho_o = (short*)alloc((long)Hsz * Esz * 2);
  short* Wt_pr   = (short*)alloc(2L * Ssz * Hsz * 2);
  short* Wt_po   = (short*)alloc(2L * Ssz * Hsz * 2);
  short* obs_b   = (short*)alloc((long)Bsz * Tsz * Esz * 2);
  short* act_b   = (short*)alloc((long)Bsz * Tsz * Asz * 2);
  short* a_pre   = (short*)alloc((long)Bsz * Tsz * Hsz * 2);
  short* ha_a    = (short*)alloc((long)Bsz * Tsz * Hsz * 2);
  short* ho_o    = (short*)alloc((long)Bsz * Tsz * Hsz * 2);
  short* s_b     = (short*)alloc((long)Bsz * Ssz * 2);
  short* h_b     = (short*)alloc((long)Bsz * Hsz * 2);
  short* sa_b    = (short*)alloc((long)Bsz * Hsz * 2);
  short* ha_b    = (short*)alloc((long)Bsz * Hsz * 2);
  short* ho_b    = (short*)alloc((long)Bsz * Hsz * 2);
  char* q = (char*)obs_b;                     // alias region (dead after precompute)
  auto alias = [&](size_t bytes) { char* r = q; q += (bytes + 255) & ~(size_t)255; return r; };
  float* gi_f    = (float*)alias((long)Bsz * 3 * Hsz * 4);
  float* gh_f    = (float*)alias((long)Bsz * 3 * Hsz * 4);
  float* haho_p  = (float*)alias(8L * PSH * 4);
  float* prpo_p  = (float*)alias(8L * PSS * 4);
  (void)ws_size; (void)in_sizes; (void)n_in; (void)out_size;

  conv_f2b<<<4096, 256, 0, stream>>>(obs,  obs_b, (long)Bsz * Tsz * Esz);
  conv_f2b<<<1024, 256, 0, stream>>>(actions, act_b, (long)Bsz * Tsz * Asz);
  conv_f2b<<<4096, 256, 0, stream>>>(W_ih, Wih_b, 3L * Hsz * Hsz);
  conv_f2b<<<4096, 256, 0, stream>>>(W_hh, Whh_b, 3L * Hsz * Hsz);

  dim3 tb(32, 8);
  transp<<<dim3(Hsz / 32, Ssz / 32), tb, 0, stream>>>(W_sa, Wt_sa_s, Hsz, 0,   Ssz, Hsz);
  transp<<<dim3(Hsz / 32, Asz / 32), tb, 0, stream>>>(W_sa, Wt_sa_a, Hsz, Ssz, Asz, Hsz);
  transp<<<dim3(Hsz / 32, Hsz / 32), tb, 0, stream>>>(W_ha, Wt_ha_h, Hsz, 0,   Hsz, Hsz);
  transp<<<dim3(Hsz / 32, Asz / 32), tb, 0, stream>>>(W_ha, Wt_ha_a, Hsz, Hsz, Asz, Hsz);
  transp<<<dim3(Hsz / 32, Hsz / 32), tb, 0, stream>>>(W_ho, Wt_ho_h, Hsz, 0,   Hsz, Hsz);
  transp<<<dim3(Hsz / 32, Esz / 32), tb, 0, stream>>>(W_ho, Wt_ho_o, Hsz, Hsz, Esz, Hsz);
  transp<<<dim3(2 * Ssz / 32, Hsz / 32), tb, 0, stream>>>(W_prior, Wt_pr, 2 * Ssz, 0, Hsz, 2 * Ssz);
  transp<<<dim3(2 * Ssz / 32, Hsz / 32), tb, 0, stream>>>(W_post,  Wt_po, 2 * Ssz, 0, Hsz, 2 * Ssz);

  init_kernel<<<2048, 256, 0, stream>>>(prev_hidden, prev_state, out, h_b, s_b);

  {
    GArg g0 = mk(act_b, Asz, Wt_sa_a, Asz, b_sa, nullptr, 0, nullptr, 0, 0, a_pre, Hsz);
    GArg g1 = mk(act_b, Asz, Wt_ha_a, Asz, b_ha, nullptr, 0, nullptr, 0, 0, ha_a, Hsz);
    gemm_bt<1, 0, 0, 0, 1><<<dim3(Hsz / 128, (Bsz * Tsz) / 128, 2), 256, 0, stream>>>(g0, g1, Asz);
  }
  {
    GArg g0 = mk(obs_b, Esz, Wt_ho_o, Esz, b_ho, nullptr, 0, nullptr, 0, 0, ho_o, Hsz);
    gemm_bt<1, 0, 0, 0, 1><<<dim3(Hsz / 128, (Bsz * Tsz) / 128, 1), 256, 0, stream>>>(g0, g0, Esz);
  }

  const long ldPre = (long)Tsz * Hsz;
  for (int t = 0; t < TM1; ++t) {
    {
      GArg g0 = mk(s_b, Ssz, Wt_sa_s, Ssz, nullptr, a_pre + (long)t * Hsz, ldPre,
                   nullptr, 0, 0, sa_b, Hsz);
      gemm_bt<0, 1, 1, 0, 1><<<dim3(16, 2, 1), 256, 0, stream>>>(g0, g0, Ssz);
    }
    {
      GArg g0 = mk(sa_b, Hsz, Wih_b, Hsz, nullptr, nullptr, 0, gi_f, 3 * Hsz, 0, nullptr, 0);
      GArg g1 = mk(h_b,  Hsz, Whh_b, Hsz, nullptr, nullptr, 0, gh_f, 3 * Hsz, 0, nullptr, 0);
      gemm_bt<0, 0, 0, 1, 0><<<dim3(48, 2, 2), 256, 0, stream>>>(g0, g1, Hsz);
    }
    gru_kernel<<<2048, 256, 0, stream>>>(gi_f, gh_f, b_ih, b_hh,
                                         out + (long)t * Hsz, out + (long)(t + 1) * Hsz, h_b);
    {
      GArg g0 = mk(h_b, Hsz, Wt_ha_h, Hsz, nullptr, nullptr, 0, haho_p, Hsz, PSH, nullptr, 0);
      GArg g1 = mk(h_b, Hsz, Wt_ho_h, Hsz, nullptr, nullptr, 0, haho_p + 4L * PSH, Hsz, PSH, nullptr, 0);
      gemm_bt<0, 0, 0, 1, 0><<<dim3(16, 2, 8), 256, 0, stream>>>(g0, g1, Hsz / 4);
    }
    reduce_relu4<<<dim3(512, 2), 256, 0, stream>>>(haho_p, ha_a, ho_o, ha_b, ho_b, t);
    {
      GArg g0 = mk(ha_b, Hsz, Wt_pr, Hsz, nullptr, nullptr, 0, prpo_p, 2 * Ssz, PSS, nullptr, 0);
      GArg g1 = mk(ho_b, Hsz, Wt_po, Hsz, nullptr, nullptr, 0, prpo_p + 4L * PSS, 2 * Ssz, PSS, nullptr, 0);
      gemm_bt<0, 0, 0, 1, 0><<<dim3(8, 2, 8), 256, 0, stream>>>(g0, g1, Hsz / 4);
    }
    sample_kernel<<<512, 256, 0, stream>>>(prpo_p, b_prior, b_post,
                                           prior_noise, post_noise, out, s_b, t);
  }
}